// Round 4
// baseline (757.853 us; speedup 1.0000x reference)
//
#include <hip/hip_runtime.h>
#include <stdint.h>
#include <stddef.h>

// MinGRU: B=8, S=4096, DX=DH=1024.
// Interface (established R1-R3): ALL inputs fp32, output fp32.
// Internals: weights/x cast to bf16 for MFMA; scan + epilogue in fp32.
//
// Pipeline:
//   0) conv weights fp32->bf16 (ws)
//   1) gate_gemm (dual MFMA GEMM, x conversion fused into LDS staging):
//      k=x·Wz^T+bz, th=x·Wh^T+bh; epilogue a=sigmoid(-k), v=sigmoid(k)*g(th),
//      g(t)= t>=0 ? t+0.5 : sigmoid(t)   -> aB,vB (bf16, ws)
//   2) 3-phase chunked scan h_t = a_t h_{t-1} + v_t (h_0=0), chunks L=64;
//      phase3 writes h bf16 in-place over vB
//   3) out_gemm: out = h·Wo^T + bo -> d_out (fp32)
//   + sample checkers w/ scalar fallbacks on both GEMM stages (insurance).

typedef __bf16 bf16;
typedef __bf16 bf16x8 __attribute__((ext_vector_type(8)));
typedef float f32x4 __attribute__((ext_vector_type(4)));

// ---------------- fp32 -> bf16 weight conversion ------------------------------
__global__ __launch_bounds__(256)
void conv_w(const float* __restrict__ src, bf16* __restrict__ dst, int n4) {
  int i = blockIdx.x * 256 + threadIdx.x;
  if (i >= n4) return;
  float4 v = ((const float4*)src)[i];
  bf16 o[4] = {(bf16)v.x, (bf16)v.y, (bf16)v.z, (bf16)v.w};
  *(uint64_t*)(dst + 4 * (size_t)i) = *(uint64_t*)o;
}

// ---------------- gate GEMM: dual output, 128x128 tile, BK=32 -----------------
__global__ __launch_bounds__(256, 2)
void gate_gemm(const float* __restrict__ xf,
               const bf16* __restrict__ Wz, const bf16* __restrict__ Wh,
               const float* __restrict__ bzf, const float* __restrict__ bhf,
               bf16* __restrict__ aB, bf16* __restrict__ vB) {
  __shared__ __align__(16) bf16 As [128 * 32];
  __shared__ __align__(16) bf16 Bzs[128 * 32];
  __shared__ __align__(16) bf16 Bhs[128 * 32];

  const int lane = threadIdx.x & 63;
  const int wave = threadIdx.x >> 6;
  const int wm = wave >> 1, wn = wave & 1;    // 2x2 waves of 64x64
  const int tileM = blockIdx.y * 128;
  const int tileN = blockIdx.x * 128;
  const int q = lane >> 4, r = lane & 15;     // MFMA quad / m(or n)-in-frag
  const int srow = lane >> 2;                 // staging row within 16-row chunk
  const int scol = (lane & 3) * 8;            // staging k-offset (elements)

  int lofs[2]; size_t xoff[2], woff[2];
#pragma unroll
  for (int j = 0; j < 2; ++j) {
    const int cid = j * 4 + wave;             // 0..7 -> 16-row chunk
    const int row = cid * 16 + srow;
    lofs[j] = cid * 512 + lane * 8;           // == row*32 + scol
    xoff[j] = (size_t)(tileM + row) * 1024 + scol;
    woff[j] = (size_t)(tileN + row) * 1024 + scol;
  }

  const bf16* pA[4]; const bf16* pBz[4]; const bf16* pBh[4];
#pragma unroll
  for (int f = 0; f < 4; ++f) {
    pA[f]  = As  + (wm * 64 + f * 16 + r) * 32 + q * 8;  // A[m=lane&15][k=q*8+j]
    pBz[f] = Bzs + (wn * 64 + f * 16 + r) * 32 + q * 8;  // B[k=q*8+j][n=lane&15]
    pBh[f] = Bhs + (wn * 64 + f * 16 + r) * 32 + q * 8;
  }

  f32x4 accz[4][4], acch[4][4];
#pragma unroll
  for (int i = 0; i < 4; ++i)
#pragma unroll
    for (int j = 0; j < 4; ++j) {
      accz[i][j] = (f32x4){0.f, 0.f, 0.f, 0.f};
      acch[i][j] = (f32x4){0.f, 0.f, 0.f, 0.f};
    }

  for (int k0 = 0; k0 < 1024; k0 += 32) {
    __syncthreads();
#pragma unroll
    for (int j = 0; j < 2; ++j) {
      const float4* g = (const float4*)(xf + xoff[j] + k0);
      float4 u0 = g[0], u1 = g[1];
      bf16x8 w = {(bf16)u0.x, (bf16)u0.y, (bf16)u0.z, (bf16)u0.w,
                  (bf16)u1.x, (bf16)u1.y, (bf16)u1.z, (bf16)u1.w};
      *(bf16x8*)(As + lofs[j]) = w;
      *(bf16x8*)(Bzs + lofs[j]) = *(const bf16x8*)(Wz + woff[j] + k0);
      *(bf16x8*)(Bhs + lofs[j]) = *(const bf16x8*)(Wh + woff[j] + k0);
    }
    __syncthreads();

    bf16x8 af[4];
#pragma unroll
    for (int fm = 0; fm < 4; ++fm) af[fm] = *(const bf16x8*)pA[fm];
#pragma unroll
    for (int fn = 0; fn < 4; ++fn) {
      bf16x8 bz8 = *(const bf16x8*)pBz[fn];
      bf16x8 bh8 = *(const bf16x8*)pBh[fn];
#pragma unroll
      for (int fm = 0; fm < 4; ++fm) {
        accz[fm][fn] = __builtin_amdgcn_mfma_f32_16x16x32_bf16(af[fm], bz8, accz[fm][fn], 0, 0, 0);
        acch[fm][fn] = __builtin_amdgcn_mfma_f32_16x16x32_bf16(af[fm], bh8, acch[fm][fn], 0, 0, 0);
      }
    }
  }

  // C/D: col=lane&15, row=(lane>>4)*4+i  (m89/m91)
#pragma unroll
  for (int fn = 0; fn < 4; ++fn) {
    const int n = tileN + wn * 64 + fn * 16 + r;
    const float bzv = bzf[n], bhv = bhf[n];
#pragma unroll
    for (int fm = 0; fm < 4; ++fm) {
      const int m0 = tileM + wm * 64 + fm * 16 + q * 4;
#pragma unroll
      for (int i = 0; i < 4; ++i) {
        float kv = accz[fm][fn][i] + bzv;
        float tv = acch[fm][fn][i] + bhv;
        float e   = __expf(-kv);
        float inv = 1.f / (1.f + e);        // z = sigmoid(k)
        float a   = e * inv;                // 1-z = sigmoid(-k)
        float g   = (tv >= 0.f) ? (tv + 0.5f) : (1.f / (1.f + __expf(-tv)));
        size_t idx = (size_t)(m0 + i) * 1024 + n;
        aB[idx] = (bf16)a;
        vB[idx] = (bf16)(inv * g);
      }
    }
  }
}

// ---------------- gate check + scalar fallback --------------------------------
__global__ __launch_bounds__(256)
void chk_gate(const float* __restrict__ xf,
              const bf16* __restrict__ Wz, const bf16* __restrict__ Wh,
              const float* __restrict__ bzf, const float* __restrict__ bhf,
              const bf16* __restrict__ aB, const bf16* __restrict__ vB,
              int* __restrict__ badA) {
  int i = blockIdx.x * 256 + threadIdx.x;          // 0..1023
  int m = (i * 12347) & 32767;
  int n = (i * 4099) & 1023;
  float kz = 0.f, kh = 0.f;
  for (int k = 0; k < 1024; ++k) {
    float xv = (float)(bf16)xf[(size_t)m * 1024 + k];
    kz = fmaf(xv, (float)Wz[(size_t)n * 1024 + k], kz);
    kh = fmaf(xv, (float)Wh[(size_t)n * 1024 + k], kh);
  }
  kz += bzf[n]; kh += bhf[n];
  float e = __expf(-kz), inv = 1.f / (1.f + e);
  float a = e * inv;
  float g = (kh >= 0.f) ? (kh + 0.5f) : (1.f / (1.f + __expf(-kh)));
  float v = inv * g;
  size_t idx = (size_t)m * 1024 + n;
  int ok = (fabsf((float)aB[idx] - a) <= 0.04f) &&
           (fabsf((float)vB[idx] - v) <= 0.08f);   // NaN -> not ok
  if (!ok) atomicAdd(badA, 1);
}

__global__ __launch_bounds__(256)
void fb_gate(const int* __restrict__ badA, const float* __restrict__ xf,
             const bf16* __restrict__ Wz, const bf16* __restrict__ Wh,
             const float* __restrict__ bzf, const float* __restrict__ bhf,
             bf16* __restrict__ aB, bf16* __restrict__ vB) {
  if (*badA < 4) return;                           // MFMA path verified: no-op
  const int n = (blockIdx.x & 3) * 256 + threadIdx.x;
  const int m0 = (blockIdx.x >> 2) * 16;
  for (int mi = 0; mi < 16; ++mi) {
    const int m = m0 + mi;
    float kz = 0.f, kh = 0.f;
    for (int k = 0; k < 1024; ++k) {
      float xv = (float)(bf16)xf[(size_t)m * 1024 + k];
      kz = fmaf(xv, (float)Wz[(size_t)n * 1024 + k], kz);
      kh = fmaf(xv, (float)Wh[(size_t)n * 1024 + k], kh);
    }
    kz += bzf[n]; kh += bhf[n];
    float e = __expf(-kz), inv = 1.f / (1.f + e);
    float a = e * inv;
    float g = (kh >= 0.f) ? (kh + 0.5f) : (1.f / (1.f + __expf(-kh)));
    size_t idx = (size_t)m * 1024 + n;
    aB[idx] = (bf16)a;
    vB[idx] = (bf16)(inv * g);
  }
}

// ---------------- scan: h_t = a_t h_{t-1} + v_t, chunks L=64, C=64 ------------
__global__ __launch_bounds__(256)
void scan_phase1(const bf16* __restrict__ aB, const bf16* __restrict__ vB,
                 float* __restrict__ Ac, float* __restrict__ Vc) {
  const int tid = blockIdx.x * 256 + threadIdx.x;  // B*C*H = 524288
  const int h = tid & 1023, c = (tid >> 10) & 63, b = tid >> 16;
  const int idx = (b * 4096 + c * 64) * 1024 + h;
  float A = 1.f, V = 0.f;
#pragma unroll 8
  for (int t = 0; t < 64; ++t) {
    float a = (float)aB[idx + t * 1024];
    float v = (float)vB[idx + t * 1024];
    V = fmaf(a, V, v);
    A *= a;
  }
  Ac[tid] = A; Vc[tid] = V;
}

__global__ __launch_bounds__(256)
void scan_phase2(const float* __restrict__ Ac, const float* __restrict__ Vc,
                 float* __restrict__ Hin) {
  const int tid = blockIdx.x * 256 + threadIdx.x;  // B*H = 8192
  const int h = tid & 1023, b = tid >> 10;
  float carry = 0.f;
  for (int c = 0; c < 64; ++c) {
    const int idx = (b * 64 + c) * 1024 + h;
    Hin[idx] = carry;
    carry = fmaf(Ac[idx], carry, Vc[idx]);
  }
}

// hB aliases vB (in-place): no restrict on those, per-slot load->store order.
__global__ __launch_bounds__(256)
void scan_phase3(const bf16* __restrict__ aB, const bf16* vB,
                 const float* __restrict__ Hin, bf16* hB) {
  const int tid = blockIdx.x * 256 + threadIdx.x;
  const int h = tid & 1023, c = (tid >> 10) & 63, b = tid >> 16;
  const int idx = (b * 4096 + c * 64) * 1024 + h;
  float hcur = Hin[tid];
#pragma unroll 8
  for (int t = 0; t < 64; ++t) {
    float a = (float)aB[idx + t * 1024];
    float v = (float)vB[idx + t * 1024];
    hcur = fmaf(a, hcur, v);
    hB[idx + t * 1024] = (bf16)hcur;
  }
}

// ---------------- out GEMM -> fp32 output -------------------------------------
__global__ __launch_bounds__(256, 2)
void out_gemm(const bf16* __restrict__ H, const bf16* __restrict__ Wo,
              const float* __restrict__ bof, float* __restrict__ O) {
  __shared__ __align__(16) bf16 As[128 * 32];
  __shared__ __align__(16) bf16 Bs[128 * 32];

  const int lane = threadIdx.x & 63;
  const int wave = threadIdx.x >> 6;
  const int wm = wave >> 1, wn = wave & 1;
  const int tileM = blockIdx.y * 128;
  const int tileN = blockIdx.x * 128;
  const int q = lane >> 4, r = lane & 15;
  const int srow = lane >> 2;
  const int scol = (lane & 3) * 8;

  int lofs[2]; size_t aoff[2], woff[2];
#pragma unroll
  for (int j = 0; j < 2; ++j) {
    const int cid = j * 4 + wave;
    const int row = cid * 16 + srow;
    lofs[j] = cid * 512 + lane * 8;
    aoff[j] = (size_t)(tileM + row) * 1024 + scol;
    woff[j] = (size_t)(tileN + row) * 1024 + scol;
  }
  const bf16* pA[4]; const bf16* pB[4];
#pragma unroll
  for (int f = 0; f < 4; ++f) {
    pA[f] = As + (wm * 64 + f * 16 + r) * 32 + q * 8;
    pB[f] = Bs + (wn * 64 + f * 16 + r) * 32 + q * 8;
  }

  f32x4 acc[4][4];
#pragma unroll
  for (int i = 0; i < 4; ++i)
#pragma unroll
    for (int j = 0; j < 4; ++j) acc[i][j] = (f32x4){0.f, 0.f, 0.f, 0.f};

  for (int k0 = 0; k0 < 1024; k0 += 32) {
    __syncthreads();
#pragma unroll
    for (int j = 0; j < 2; ++j) {
      *(bf16x8*)(As + lofs[j]) = *(const bf16x8*)(H  + aoff[j] + k0);
      *(bf16x8*)(Bs + lofs[j]) = *(const bf16x8*)(Wo + woff[j] + k0);
    }
    __syncthreads();

    bf16x8 af[4];
#pragma unroll
    for (int fm = 0; fm < 4; ++fm) af[fm] = *(const bf16x8*)pA[fm];
#pragma unroll
    for (int fn = 0; fn < 4; ++fn) {
      bf16x8 b8 = *(const bf16x8*)pB[fn];
#pragma unroll
      for (int fm = 0; fm < 4; ++fm)
        acc[fm][fn] = __builtin_amdgcn_mfma_f32_16x16x32_bf16(af[fm], b8, acc[fm][fn], 0, 0, 0);
    }
  }

#pragma unroll
  for (int fn = 0; fn < 4; ++fn) {
    const int n = tileN + wn * 64 + fn * 16 + r;
    const float bov = bof[n];
#pragma unroll
    for (int fm = 0; fm < 4; ++fm) {
      const int m0 = tileM + wm * 64 + fm * 16 + q * 4;
#pragma unroll
      for (int i = 0; i < 4; ++i)
        O[(size_t)(m0 + i) * 1024 + n] = acc[fm][fn][i] + bov;   // fp32 store
    }
  }
}

// ---------------- out check + scalar fallback ---------------------------------
__global__ __launch_bounds__(256)
void chk_out(const bf16* __restrict__ H, const bf16* __restrict__ Wo,
             const float* __restrict__ bof, const float* __restrict__ O,
             int* __restrict__ badB) {
  int i = blockIdx.x * 256 + threadIdx.x;
  int m = (i * 12347) & 32767;
  int n = (i * 4099) & 1023;
  float acc = 0.f;
  for (int k = 0; k < 1024; ++k)
    acc = fmaf((float)H[(size_t)m * 1024 + k], (float)Wo[(size_t)n * 1024 + k], acc);
  acc += bof[n];
  int ok = fabsf(O[(size_t)m * 1024 + n] - acc) <= 0.05f;
  if (!ok) atomicAdd(badB, 1);
}

__global__ __launch_bounds__(256)
void fb_out(const int* __restrict__ badB, const bf16* __restrict__ H,
            const bf16* __restrict__ Wo, const float* __restrict__ bof,
            float* __restrict__ O) {
  if (*badB < 4) return;
  const int n = (blockIdx.x & 3) * 256 + threadIdx.x;
  const int m0 = (blockIdx.x >> 2) * 16;
  for (int mi = 0; mi < 16; ++mi) {
    const int m = m0 + mi;
    float acc = 0.f;
    for (int k = 0; k < 1024; ++k)
      acc = fmaf((float)H[(size_t)m * 1024 + k], (float)Wo[(size_t)n * 1024 + k], acc);
    O[(size_t)m * 1024 + n] = acc + bof[n];
  }
}

// ------------------------------- launch ---------------------------------------
extern "C" void kernel_launch(void* const* d_in, const int* in_sizes, int n_in,
                              void* d_out, int out_size, void* d_ws, size_t ws_size,
                              hipStream_t stream) {
  char* ws = (char*)d_ws;
  // ws: aB 0(64MB) | vB 64MB(64MB, ->h in-place) | Ac 128MB | Vc +2MB | Hin +2MB
  //     | flags 134MB(8B) | wzb 134MB+16KB (2MB) | whb | wob    total ~141MB
  bf16*  aB  = (bf16*)(ws);
  bf16*  vB  = (bf16*)(ws + 67108864ull);
  float* Ac  = (float*)(ws + 134217728ull);
  float* Vc  = (float*)(ws + 136314880ull);
  float* Hin = (float*)(ws + 138412032ull);
  int*   flags = (int*)(ws + 140509184ull);   // [0]=badA, [1]=badB
  bf16*  wzb = (bf16*)(ws + 140525568ull);
  bf16*  whb = wzb + 1048576;
  bf16*  wob = whb + 1048576;

  const float* xf  = (const float*)d_in[0];
  const float* bzf = (const float*)d_in[2];
  const float* bhf = (const float*)d_in[4];
  const float* bof = (const float*)d_in[6];

  hipMemsetAsync(flags, 0, 8, stream);
  conv_w<<<1024, 256, 0, stream>>>((const float*)d_in[1], wzb, 262144);
  conv_w<<<1024, 256, 0, stream>>>((const float*)d_in[3], whb, 262144);
  conv_w<<<1024, 256, 0, stream>>>((const float*)d_in[5], wob, 262144);

  dim3 blk(256);
  dim3 gg(8, 256);  // (N/128, M/128), M=32768 N=1024

  gate_gemm<<<gg, blk, 0, stream>>>(xf, wzb, whb, bzf, bhf, aB, vB);
  chk_gate<<<4, blk, 0, stream>>>(xf, wzb, whb, bzf, bhf, aB, vB, flags);
  fb_gate<<<8192, blk, 0, stream>>>(flags, xf, wzb, whb, bzf, bhf, aB, vB);

  scan_phase1<<<2048, blk, 0, stream>>>(aB, vB, Ac, Vc);
  scan_phase2<<<32,   blk, 0, stream>>>(Ac, Vc, Hin);
  scan_phase3<<<2048, blk, 0, stream>>>(aB, vB, Hin, vB /* in-place h */);

  out_gemm<<<gg, blk, 0, stream>>>(vB, wob, bof, (float*)d_out);
  chk_out<<<4, blk, 0, stream>>>(vB, wob, bof, (const float*)d_out, flags + 1);
  fb_out<<<8192, blk, 0, stream>>>(flags + 1, vB, wob, bof, (float*)d_out);
}

// Round 6
// 712.606 us; speedup vs baseline: 1.0635x; 1.0635x over previous
//
#include <hip/hip_runtime.h>
#include <stdint.h>
#include <stddef.h>

// MinGRU: B=8, S=4096, DX=DH=1024. All inputs fp32, output fp32 (est. R1-R4).
// R6: fix R5's fatal bug — conv_b for x covered only 1/4 of the tensor (rest
// stayed 0xAA poison; checkers validated against the same poisoned xb, so they
// passed by construction). conv_b is now grid-stride. Everything else = R5:
// global_load_lds staging in both GEMMs, 8-wide scan, checkers retained.

typedef __bf16 bf16;
typedef __bf16 bf16x8 __attribute__((ext_vector_type(8)));
typedef float f32x4 __attribute__((ext_vector_type(4)));

#define DEV __device__ __forceinline__

DEV void gload_lds16(const bf16* g, bf16* l) {
  // per-lane gptr; LDS dest = wave-uniform base + lane*16B (implicit scatter)
  __builtin_amdgcn_global_load_lds((const __attribute__((address_space(1))) void*)g,
                                   (__attribute__((address_space(3))) void*)l,
                                   16, 0, 0);
}

// ---------------- fp32 -> bf16 conversion (grid-stride, bug-class-proof) ------
__global__ __launch_bounds__(256)
void conv_b(const float* __restrict__ src, bf16* __restrict__ dst, int n4) {
  const int stride = gridDim.x * 256;
  for (int i = blockIdx.x * 256 + threadIdx.x; i < n4; i += stride) {
    float4 v = ((const float4*)src)[i];
    bf16 o[4] = {(bf16)v.x, (bf16)v.y, (bf16)v.z, (bf16)v.w};
    *(uint64_t*)(dst + 4 * (size_t)i) = *(uint64_t*)o;
  }
}

// ---------------- gate GEMM: dual output, 128x128 tile, BK=32, DMA staging ----
__global__ __launch_bounds__(256, 2)
void gate_gemm(const bf16* __restrict__ X,
               const bf16* __restrict__ Wz, const bf16* __restrict__ Wh,
               const float* __restrict__ bzf, const float* __restrict__ bhf,
               bf16* __restrict__ aB, bf16* __restrict__ vB) {
  __shared__ __align__(16) bf16 As [128 * 32];
  __shared__ __align__(16) bf16 Bzs[128 * 32];
  __shared__ __align__(16) bf16 Bhs[128 * 32];

  const int lane = threadIdx.x & 63;
  const int wave = threadIdx.x >> 6;
  const int wm = wave >> 1, wn = wave & 1;    // 2x2 waves of 64x64
  const int tileM = blockIdx.y * 128;
  const int tileN = blockIdx.x * 128;
  const int q = lane >> 4, r = lane & 15;     // MFMA quad / m(or n)-in-frag
  const int srow = lane >> 2;                 // staging row within 16-row chunk
  const int scol = (lane & 3) * 8;            // staging k-offset (elements)

  const bf16* ga[2]; const bf16* gz[2]; const bf16* gh[2];
  bf16* la[2]; bf16* lz[2]; bf16* lh[2];
#pragma unroll
  for (int j = 0; j < 2; ++j) {
    const int cid = j * 4 + wave;             // 0..7 -> 16-row chunk
    const int row = cid * 16 + srow;
    ga[j] = X  + (size_t)(tileM + row) * 1024 + scol;
    gz[j] = Wz + (size_t)(tileN + row) * 1024 + scol;
    gh[j] = Wh + (size_t)(tileN + row) * 1024 + scol;
    la[j] = As  + cid * 512;                  // wave-uniform LDS base
    lz[j] = Bzs + cid * 512;
    lh[j] = Bhs + cid * 512;
  }

  const bf16* pA[4]; const bf16* pBz[4]; const bf16* pBh[4];
#pragma unroll
  for (int f = 0; f < 4; ++f) {
    pA[f]  = As  + (wm * 64 + f * 16 + r) * 32 + q * 8;  // A[m=r][k=q*8+j]
    pBz[f] = Bzs + (wn * 64 + f * 16 + r) * 32 + q * 8;  // B[n=r][k=q*8+j]
    pBh[f] = Bhs + (wn * 64 + f * 16 + r) * 32 + q * 8;
  }

  f32x4 accz[4][4], acch[4][4];
#pragma unroll
  for (int i = 0; i < 4; ++i)
#pragma unroll
    for (int j = 0; j < 4; ++j) {
      accz[i][j] = (f32x4){0.f, 0.f, 0.f, 0.f};
      acch[i][j] = (f32x4){0.f, 0.f, 0.f, 0.f};
    }

  for (int k0 = 0; k0 < 1024; k0 += 32) {
    __syncthreads();
#pragma unroll
    for (int j = 0; j < 2; ++j) {
      gload_lds16(ga[j] + k0, la[j]);
      gload_lds16(gz[j] + k0, lz[j]);
      gload_lds16(gh[j] + k0, lh[j]);
    }
    __syncthreads();   // drains vmcnt before barrier (compiler-inserted)

    bf16x8 af[4];
#pragma unroll
    for (int fm = 0; fm < 4; ++fm) af[fm] = *(const bf16x8*)pA[fm];
#pragma unroll
    for (int fn = 0; fn < 4; ++fn) {
      bf16x8 bz8 = *(const bf16x8*)pBz[fn];
      bf16x8 bh8 = *(const bf16x8*)pBh[fn];
#pragma unroll
      for (int fm = 0; fm < 4; ++fm) {
        accz[fm][fn] = __builtin_amdgcn_mfma_f32_16x16x32_bf16(af[fm], bz8, accz[fm][fn], 0, 0, 0);
        acch[fm][fn] = __builtin_amdgcn_mfma_f32_16x16x32_bf16(af[fm], bh8, acch[fm][fn], 0, 0, 0);
      }
    }
  }

  // C/D: col=lane&15, row=(lane>>4)*4+i  (m89/m91)
#pragma unroll
  for (int fn = 0; fn < 4; ++fn) {
    const int n = tileN + wn * 64 + fn * 16 + r;
    const float bzv = bzf[n], bhv = bhf[n];
#pragma unroll
    for (int fm = 0; fm < 4; ++fm) {
      const int m0 = tileM + wm * 64 + fm * 16 + q * 4;
#pragma unroll
      for (int i = 0; i < 4; ++i) {
        float kv = accz[fm][fn][i] + bzv;
        float tv = acch[fm][fn][i] + bhv;
        float e   = __expf(-kv);
        float inv = 1.f / (1.f + e);        // z = sigmoid(k)
        float a   = e * inv;                // 1-z = sigmoid(-k)
        float g   = (tv >= 0.f) ? (tv + 0.5f) : (1.f / (1.f + __expf(-tv)));
        size_t idx = (size_t)(m0 + i) * 1024 + n;
        aB[idx] = (bf16)a;
        vB[idx] = (bf16)(inv * g);
      }
    }
  }
}

// ---------------- gate check + scalar fallback (insurance) --------------------
__global__ __launch_bounds__(256)
void chk_gate(const bf16* __restrict__ X,
              const bf16* __restrict__ Wz, const bf16* __restrict__ Wh,
              const float* __restrict__ bzf, const float* __restrict__ bhf,
              const bf16* __restrict__ aB, const bf16* __restrict__ vB,
              int* __restrict__ badA) {
  int i = blockIdx.x * 256 + threadIdx.x;          // 0..1023
  int m = (i * 12347) & 32767;
  int n = (i * 4099) & 1023;
  float kz = 0.f, kh = 0.f;
  for (int k = 0; k < 1024; ++k) {
    float xv = (float)X[(size_t)m * 1024 + k];
    kz = fmaf(xv, (float)Wz[(size_t)n * 1024 + k], kz);
    kh = fmaf(xv, (float)Wh[(size_t)n * 1024 + k], kh);
  }
  kz += bzf[n]; kh += bhf[n];
  float e = __expf(-kz), inv = 1.f / (1.f + e);
  float a = e * inv;
  float g = (kh >= 0.f) ? (kh + 0.5f) : (1.f / (1.f + __expf(-kh)));
  float v = inv * g;
  size_t idx = (size_t)m * 1024 + n;
  int ok = (fabsf((float)aB[idx] - a) <= 0.04f) &&
           (fabsf((float)vB[idx] - v) <= 0.08f);   // NaN -> not ok
  if (!ok) atomicAdd(badA, 1);
}

__global__ __launch_bounds__(256)
void fb_gate(const int* __restrict__ badA, const bf16* __restrict__ X,
             const bf16* __restrict__ Wz, const bf16* __restrict__ Wh,
             const float* __restrict__ bzf, const float* __restrict__ bhf,
             bf16* __restrict__ aB, bf16* __restrict__ vB) {
  if (*badA < 4) return;                           // MFMA path OK: no-op
  const int n = (blockIdx.x & 3) * 256 + threadIdx.x;
  const int m0 = (blockIdx.x >> 2) * 16;
  for (int mi = 0; mi < 16; ++mi) {
    const int m = m0 + mi;
    float kz = 0.f, kh = 0.f;
    for (int k = 0; k < 1024; ++k) {
      float xv = (float)X[(size_t)m * 1024 + k];
      kz = fmaf(xv, (float)Wz[(size_t)n * 1024 + k], kz);
      kh = fmaf(xv, (float)Wh[(size_t)n * 1024 + k], kh);
    }
    kz += bzf[n]; kh += bhf[n];
    float e = __expf(-kz), inv = 1.f / (1.f + e);
    float a = e * inv;
    float g = (kh >= 0.f) ? (kh + 0.5f) : (1.f / (1.f + __expf(-kh)));
    size_t idx = (size_t)m * 1024 + n;
    aB[idx] = (bf16)a;
    vB[idx] = (bf16)(inv * g);
  }
}

// ---------------- scan: h_t = a_t h_{t-1} + v_t, chunks L=64, 8-wide ----------
__global__ __launch_bounds__(256)
void scan_phase1(const bf16* __restrict__ aB, const bf16* __restrict__ vB,
                 float* __restrict__ Ac, float* __restrict__ Vc) {
  const int tid = blockIdx.x * 256 + threadIdx.x;  // B*C*(H/8) = 65536
  const int hg = tid & 127, c = (tid >> 7) & 63, b = tid >> 13;
  const size_t base = (size_t)(b * 4096 + c * 64) * 1024 + hg * 8;
  float A[8], V[8];
#pragma unroll
  for (int j = 0; j < 8; ++j) { A[j] = 1.f; V[j] = 0.f; }
#pragma unroll 8
  for (int t = 0; t < 64; ++t) {
    bf16x8 a8 = *(const bf16x8*)(aB + base + (size_t)t * 1024);
    bf16x8 v8 = *(const bf16x8*)(vB + base + (size_t)t * 1024);
#pragma unroll
    for (int j = 0; j < 8; ++j) {
      float a = (float)a8[j];
      V[j] = fmaf(a, V[j], (float)v8[j]);
      A[j] *= a;
    }
  }
  const size_t o = (size_t)(b * 64 + c) * 1024 + hg * 8;
#pragma unroll
  for (int j = 0; j < 8; ++j) { Ac[o + j] = A[j]; Vc[o + j] = V[j]; }
}

__global__ __launch_bounds__(256)
void scan_phase2(const float* __restrict__ Ac, const float* __restrict__ Vc,
                 float* __restrict__ Hin) {
  const int tid = blockIdx.x * 256 + threadIdx.x;  // B*H = 8192
  const int h = tid & 1023, b = tid >> 10;
  float carry = 0.f;
  for (int c = 0; c < 64; ++c) {
    const int idx = (b * 64 + c) * 1024 + h;
    Hin[idx] = carry;
    carry = fmaf(Ac[idx], carry, Vc[idx]);
  }
}

// hB aliases vB (in-place): no restrict on those, per-slot load->store order.
__global__ __launch_bounds__(256)
void scan_phase3(const bf16* __restrict__ aB, const bf16* vB,
                 const float* __restrict__ Hin, bf16* hB) {
  const int tid = blockIdx.x * 256 + threadIdx.x;  // 65536
  const int hg = tid & 127, c = (tid >> 7) & 63, b = tid >> 13;
  const size_t base = (size_t)(b * 4096 + c * 64) * 1024 + hg * 8;
  const size_t o = (size_t)(b * 64 + c) * 1024 + hg * 8;
  float hc[8];
#pragma unroll
  for (int j = 0; j < 8; ++j) hc[j] = Hin[o + j];
#pragma unroll 4
  for (int t = 0; t < 64; ++t) {
    bf16x8 a8 = *(const bf16x8*)(aB + base + (size_t)t * 1024);
    bf16x8 v8 = *(const bf16x8*)(vB + base + (size_t)t * 1024);
    bf16x8 h8;
#pragma unroll
    for (int j = 0; j < 8; ++j) {
      hc[j] = fmaf((float)a8[j], hc[j], (float)v8[j]);
      h8[j] = (bf16)hc[j];
    }
    *(bf16x8*)(hB + base + (size_t)t * 1024) = h8;
  }
}

// ---------------- out GEMM (DMA staging) -> fp32 output -----------------------
__global__ __launch_bounds__(256, 2)
void out_gemm(const bf16* __restrict__ H, const bf16* __restrict__ Wo,
              const float* __restrict__ bof, float* __restrict__ O) {
  __shared__ __align__(16) bf16 As[128 * 32];
  __shared__ __align__(16) bf16 Bs[128 * 32];

  const int lane = threadIdx.x & 63;
  const int wave = threadIdx.x >> 6;
  const int wm = wave >> 1, wn = wave & 1;
  const int tileM = blockIdx.y * 128;
  const int tileN = blockIdx.x * 128;
  const int q = lane >> 4, r = lane & 15;
  const int srow = lane >> 2;
  const int scol = (lane & 3) * 8;

  const bf16* ga[2]; const bf16* gb[2]; bf16* la[2]; bf16* lb[2];
#pragma unroll
  for (int j = 0; j < 2; ++j) {
    const int cid = j * 4 + wave;
    const int row = cid * 16 + srow;
    ga[j] = H  + (size_t)(tileM + row) * 1024 + scol;
    gb[j] = Wo + (size_t)(tileN + row) * 1024 + scol;
    la[j] = As + cid * 512;
    lb[j] = Bs + cid * 512;
  }
  const bf16* pA[4]; const bf16* pB[4];
#pragma unroll
  for (int f = 0; f < 4; ++f) {
    pA[f] = As + (wm * 64 + f * 16 + r) * 32 + q * 8;
    pB[f] = Bs + (wn * 64 + f * 16 + r) * 32 + q * 8;
  }

  f32x4 acc[4][4];
#pragma unroll
  for (int i = 0; i < 4; ++i)
#pragma unroll
    for (int j = 0; j < 4; ++j) acc[i][j] = (f32x4){0.f, 0.f, 0.f, 0.f};

  for (int k0 = 0; k0 < 1024; k0 += 32) {
    __syncthreads();
#pragma unroll
    for (int j = 0; j < 2; ++j) {
      gload_lds16(ga[j] + k0, la[j]);
      gload_lds16(gb[j] + k0, lb[j]);
    }
    __syncthreads();

    bf16x8 af[4];
#pragma unroll
    for (int fm = 0; fm < 4; ++fm) af[fm] = *(const bf16x8*)pA[fm];
#pragma unroll
    for (int fn = 0; fn < 4; ++fn) {
      bf16x8 b8 = *(const bf16x8*)pB[fn];
#pragma unroll
      for (int fm = 0; fm < 4; ++fm)
        acc[fm][fn] = __builtin_amdgcn_mfma_f32_16x16x32_bf16(af[fm], b8, acc[fm][fn], 0, 0, 0);
    }
  }

#pragma unroll
  for (int fn = 0; fn < 4; ++fn) {
    const int n = tileN + wn * 64 + fn * 16 + r;
    const float bov = bof[n];
#pragma unroll
    for (int fm = 0; fm < 4; ++fm) {
      const int m0 = tileM + wm * 64 + fm * 16 + q * 4;
#pragma unroll
      for (int i = 0; i < 4; ++i)
        O[(size_t)(m0 + i) * 1024 + n] = acc[fm][fn][i] + bov;   // fp32 store
    }
  }
}

// ---------------- out check + scalar fallback (insurance) ---------------------
__global__ __launch_bounds__(256)
void chk_out(const bf16* __restrict__ H, const bf16* __restrict__ Wo,
             const float* __restrict__ bof, const float* __restrict__ O,
             int* __restrict__ badB) {
  int i = blockIdx.x * 256 + threadIdx.x;
  int m = (i * 12347) & 32767;
  int n = (i * 4099) & 1023;
  float acc = 0.f;
  for (int k = 0; k < 1024; ++k)
    acc = fmaf((float)H[(size_t)m * 1024 + k], (float)Wo[(size_t)n * 1024 + k], acc);
  acc += bof[n];
  int ok = fabsf(O[(size_t)m * 1024 + n] - acc) <= 0.05f;
  if (!ok) atomicAdd(badB, 1);
}

__global__ __launch_bounds__(256)
void fb_out(const int* __restrict__ badB, const bf16* __restrict__ H,
            const bf16* __restrict__ Wo, const float* __restrict__ bof,
            float* __restrict__ O) {
  if (*badB < 4) return;
  const int n = (blockIdx.x & 3) * 256 + threadIdx.x;
  const int m0 = (blockIdx.x >> 2) * 16;
  for (int mi = 0; mi < 16; ++mi) {
    const int m = m0 + mi;
    float acc = 0.f;
    for (int k = 0; k < 1024; ++k)
      acc = fmaf((float)H[(size_t)m * 1024 + k], (float)Wo[(size_t)n * 1024 + k], acc);
    O[(size_t)m * 1024 + n] = acc + bof[n];
  }
}

// ------------------------------- launch ---------------------------------------
extern "C" void kernel_launch(void* const* d_in, const int* in_sizes, int n_in,
                              void* d_out, int out_size, void* d_ws, size_t ws_size,
                              hipStream_t stream) {
  char* ws = (char*)d_ws;
  // ws: aB 0(64MB) | vB 64MB(64MB, ->h in-place) | Ac 128MB(2MB) | Vc | Hin
  //     | flags 134MB(8B) | wzb +16KB(2MB) | whb | wob | xb 142MB(64MB) ~206MB
  bf16*  aB  = (bf16*)(ws);
  bf16*  vB  = (bf16*)(ws + 67108864ull);
  float* Ac  = (float*)(ws + 134217728ull);
  float* Vc  = (float*)(ws + 136314880ull);
  float* Hin = (float*)(ws + 138412032ull);
  int*   flags = (int*)(ws + 140509184ull);   // [0]=badA, [1]=badB
  bf16*  wzb = (bf16*)(ws + 140525568ull);
  bf16*  whb = wzb + 1048576;
  bf16*  wob = whb + 1048576;
  bf16*  xb  = (bf16*)(ws + 148914176ull);

  const float* bzf = (const float*)d_in[2];
  const float* bhf = (const float*)d_in[4];
  const float* bof = (const float*)d_in[6];

  hipMemsetAsync(flags, 0, 8, stream);
  // x: 8*4096*1024 = 33554432 floats -> n4 = 8388608 (R5 bug: was 2097152)
  conv_b<<<32768, 256, 0, stream>>>((const float*)d_in[0], xb, 8388608);
  conv_b<<<1024,  256, 0, stream>>>((const float*)d_in[1], wzb, 262144);
  conv_b<<<1024,  256, 0, stream>>>((const float*)d_in[3], whb, 262144);
  conv_b<<<1024,  256, 0, stream>>>((const float*)d_in[5], wob, 262144);

  dim3 blk(256);
  dim3 gg(8, 256);  // (N/128, M/128), M=32768 N=1024

  gate_gemm<<<gg, blk, 0, stream>>>(xb, wzb, whb, bzf, bhf, aB, vB);
  chk_gate<<<4, blk, 0, stream>>>(xb, wzb, whb, bzf, bhf, aB, vB, flags);
  fb_gate<<<8192, blk, 0, stream>>>(flags, xb, wzb, whb, bzf, bhf, aB, vB);

  scan_phase1<<<256, blk, 0, stream>>>(aB, vB, Ac, Vc);
  scan_phase2<<<32,  blk, 0, stream>>>(Ac, Vc, Hin);
  scan_phase3<<<256, blk, 0, stream>>>(aB, vB, Hin, vB /* in-place h */);

  out_gemm<<<gg, blk, 0, stream>>>(vB, wob, bof, (float*)d_out);
  chk_out<<<4, blk, 0, stream>>>(vB, wob, bof, (const float*)d_out, flags + 1);
  fb_out<<<8192, blk, 0, stream>>>(flags + 1, vB, wob, bof, (float*)d_out);
}